// Round 11
// baseline (225.357 us; speedup 1.0000x reference)
//
#include <hip/hip_runtime.h>
#include <stdint.h>

#define NB 32768
#define NPASS 4
#define FULL27 0x07FFFFFFu

// Per-band bitboard: digit d, band b (rows 3b..3b+2), bit (r*9+c).
// BOX k mask within band: 0x1C0E07 << 3k ; COL c: 0x40201 << c ; ROW r: 0x1FF << 9r
// Flat float layout: puzzle p, digit d, band b, cell j  ==  p*729 + d*81 + b*27 + j.
// Input floats are 0.0f/1.0f; we test bit-pattern != 0 (same as reference's !=0).

__device__ __forceinline__ uint32_t colfold(uint32_t w) {
    return (w | (w >> 9) | (w >> 18)) & 0x1FFu;
}
__device__ __forceinline__ uint32_t colmaj2(uint32_t w) {   // columns with >=2 bits in band
    return ((w & (w >> 9)) | ((w | (w >> 9)) & (w >> 18))) & 0x1FFu;
}
__device__ __forceinline__ uint32_t nz(uint32_t u) { return u ? 1u : 0u; }

// ---------------- FULLY FUSED: direct-load + solve + expand, one kernel ----------------
// Block = 256 threads = 4 waves; 84 puzzles/block (21/wave, 3 lanes per puzzle:
// trip = lane/3, band = lane%3; lane 63 idle).
//   LOAD:   each lane loads its own 9 runs of 27 contiguous floats via 7
//           overlapping dwordx4 loads (dword-aligned: legal on gfx9xx) and
//           builds bd[] directly. No ballots / pack-LDS / extract barriers —
//           r10 showed load width isn't pack's limiter; the ballot funnel is
//           the remaining suspect, so it's removed entirely.
//   SOLVE:  validated r6/r8 logic, cross-band exchange via __shfl, no barriers.
//   EXPAND: validated r8 block-pool float4 writeback (2 barriers).
__global__ __launch_bounds__(256, 1)
void sudoku_kernel(const uint32_t* __restrict__ in, float* __restrict__ out,
                   float* __restrict__ solved) {
    __shared__ uint32_t bpool[1914];        // expand pool: 84 * 729 bits
    const int lane = threadIdx.x & 63;
    const int wv   = threadIdx.x >> 6;
    const int trip = lane / 3;              // 0..21 (21 = idle lane 63)
    const int band = lane - trip * 3;
    const int bo1 = band == 2 ? 0 : band + 1;
    const int bo2 = band == 0 ? 2 : band - 1;
    int sl1 = trip * 3 + bo1; if (sl1 > 63) sl1 = 63;   // partner lanes
    int sl2 = trip * 3 + bo2; if (sl2 > 63) sl2 = 63;
    const int blockP = blockIdx.x * 84;                 // first puzzle of block
    const int p = blockP + wv * 21 + trip;
    const bool valid = (trip < 21) && (p < NB);
    const int pl = valid ? p : (NB - 1);    // clamped for loads

    // ---------------- LOAD: 7 overlapping dwordx4 per digit -> bd[d] ----------------
    uint32_t bd[9];
    {
        const uint32_t* src0 = in + (size_t)pl * 729 + band * 27;
        #pragma unroll
        for (int d = 0; d < 9; ++d) {
            const uint32_t* s = src0 + d * 81;
            uint4 q0 = *(const uint4*)(s + 0);    // elems 0..3
            uint4 q1 = *(const uint4*)(s + 4);    // 4..7
            uint4 q2 = *(const uint4*)(s + 8);    // 8..11
            uint4 q3 = *(const uint4*)(s + 12);   // 12..15
            uint4 q4 = *(const uint4*)(s + 16);   // 16..19
            uint4 q5 = *(const uint4*)(s + 20);   // 20..23
            uint4 q6 = *(const uint4*)(s + 23);   // 23..26 (x duplicates elem 23)
            bd[d] =  nz(q0.x)        | (nz(q0.y) << 1)  | (nz(q0.z) << 2)  | (nz(q0.w) << 3)
                  | (nz(q1.x) << 4)  | (nz(q1.y) << 5)  | (nz(q1.z) << 6)  | (nz(q1.w) << 7)
                  | (nz(q2.x) << 8)  | (nz(q2.y) << 9)  | (nz(q2.z) << 10) | (nz(q2.w) << 11)
                  | (nz(q3.x) << 12) | (nz(q3.y) << 13) | (nz(q3.z) << 14) | (nz(q3.w) << 15)
                  | (nz(q4.x) << 16) | (nz(q4.y) << 17) | (nz(q4.z) << 18) | (nz(q4.w) << 19)
                  | (nz(q5.x) << 20) | (nz(q5.y) << 21) | (nz(q5.z) << 22) | (nz(q5.w) << 23)
                  | (nz(q6.y) << 24) | (nz(q6.z) << 25) | (nz(q6.w) << 26);
        }
    }

    // ---------------- SOLVE (validated r6/r8 logic, unchanged) ----------------
    #pragma unroll 1
    for (int pass = 0; pass < NPASS; ++pass) {
        // ---------- filter 'box' (band-local) ----------
        {
            uint32_t on = 0, tw = 0, fo = 0;
            #pragma unroll
            for (int d = 0; d < 9; ++d) {
                uint32_t c = on & bd[d];
                on ^= bd[d]; fo |= tw & c; tw ^= c;
            }
            uint32_t ex1 = on & ~tw & ~fo;
            #pragma unroll
            for (int d = 0; d < 9; ++d) {
                uint32_t s = bd[d] & ex1;
                #pragma unroll
                for (int k = 0; k < 3; ++k) {
                    uint32_t bm = 0x1C0E07u << (3 * k);
                    uint32_t sm = s & bm;
                    uint32_t multi = sm & (sm - 1u);
                    uint32_t keep = (sm == 0u) ? 0xFFFFFFFFu : (~bm | (multi ? 0u : sm));
                    bd[d] &= keep;
                }
            }
        }

        // ---------- pointing 'h' (band-local) ----------
        #pragma unroll
        for (int d = 0; d < 9; ++d) {
            uint32_t w = bd[d];
            uint32_t t = (w | (w >> 1) | (w >> 2)) & 0x01249249u;
            uint32_t sum = (t & 0x1FFu) + ((t >> 9) & 0x1FFu) + ((t >> 18) & 0x1FFu);
            uint32_t single = sum & ~(sum >> 1) & 0x49u;
            uint32_t point = t & (single * 0x40201u);
            uint32_t clearm = 0;
            #pragma unroll
            for (int r = 0; r < 3; ++r) {
                uint32_t pr = (point >> (9 * r)) & 0x1FFu;
                uint32_t multi = pr & (pr - 1u);
                uint32_t segkeep = multi ? 0u : pr * 7u;
                uint32_t rc = pr ? ((0x1FFu & ~segkeep) << (9 * r)) : 0u;
                clearm |= rc;
            }
            bd[d] = w & ~clearm;
        }

        // ---------- pointing 'v' (cross-band via shuffle) ----------
        {
            uint32_t pnt[9];
            #pragma unroll
            for (int d = 0; d < 9; ++d) {
                uint32_t w = bd[d];
                uint32_t q = colfold(w);
                uint32_t u = (q & 0x49u) + ((q >> 1) & 0x49u) + ((q >> 2) & 0x49u);
                uint32_t single = u & ~(u >> 1) & 0x49u;
                pnt[d] = q & (single * 7u);
            }
            #pragma unroll
            for (int d = 0; d < 9; ++d) {
                uint32_t o = (uint32_t)__shfl((int)pnt[d], sl1, 64) |
                             (uint32_t)__shfl((int)pnt[d], sl2, 64);
                bd[d] &= ~(o * 0x40201u);
            }
        }

        // ---------- unique 'h' (band-local) ----------
        {
            uint32_t hid[9], has = 0;
            #pragma unroll
            for (int d = 0; d < 9; ++d) {
                uint32_t w = bd[d], h = 0;
                #pragma unroll
                for (int r = 0; r < 3; ++r) {
                    uint32_t x = w & (0x1FFu << (9 * r));
                    h |= (x & (x - 1u)) ? 0u : x;
                }
                hid[d] = h; has |= h;
            }
            #pragma unroll
            for (int d = 0; d < 9; ++d) bd[d] = (bd[d] & ~has) | hid[d];
        }

        // ---------- unique 'v' (cross-band via shuffle) ----------
        {
            uint32_t hid[9], has = 0;
            #pragma unroll
            for (int d = 0; d < 9; ++d) {
                uint32_t w = bd[d];
                uint32_t q0 = colfold(w), m0 = colmaj2(w);
                uint32_t ex = q0 | (m0 << 9);
                uint32_t ea = (uint32_t)__shfl((int)ex, sl1, 64);
                uint32_t eb = (uint32_t)__shfl((int)ex, sl2, 64);
                uint32_t qa = ea & 0x1FFu, ma = ea >> 9;
                uint32_t qb = eb & 0x1FFu, mb = eb >> 9;
                uint32_t ge2 = m0 | ma | mb | (q0 & qa) | (q0 & qb) | (qa & qb);
                uint32_t ex1c = (q0 | qa | qb) & ~ge2;   // column total count == 1
                hid[d] = w & ((ex1c & q0) * 0x40201u);
                has |= hid[d];
            }
            #pragma unroll
            for (int d = 0; d < 9; ++d) bd[d] = (bd[d] & ~has) | hid[d];
        }

        // ---------- unique 'box' (band-local) ----------
        {
            uint32_t hid[9], has = 0;
            #pragma unroll
            for (int d = 0; d < 9; ++d) {
                uint32_t w = bd[d], h = 0;
                #pragma unroll
                for (int k = 0; k < 3; ++k) {
                    uint32_t x = w & (0x1C0E07u << (3 * k));
                    h |= (x & (x - 1u)) ? 0u : x;
                }
                hid[d] = h; has |= h;
            }
            #pragma unroll
            for (int d = 0; d < 9; ++d) bd[d] = (bd[d] & ~has) | hid[d];
        }

        // ---------- doubles 'v' twice (cross-band via shuffle) ----------
        #pragma unroll 1
        for (int rep = 0; rep < 2; ++rep) {
            uint32_t on = 0, tw = 0, fo = 0;
            #pragma unroll
            for (int d = 0; d < 9; ++d) {
                uint32_t c = on & bd[d];
                on ^= bd[d]; fo |= tw & c; tw ^= c;
            }
            uint32_t ex2 = tw & ~on & ~fo;
            uint32_t Q[9], K[9];
            #pragma unroll
            for (int d = 0; d < 9; ++d) { Q[d] = bd[d] & ex2; K[d] = 0u; }
            #pragma unroll
            for (int d1 = 0; d1 < 9; ++d1)
                #pragma unroll
                for (int d2 = d1 + 1; d2 < 9; ++d2) {
                    uint32_t P = Q[d1] & Q[d2];
                    uint32_t f0 = colfold(P), g0 = colmaj2(P);
                    uint32_t ex = f0 | (g0 << 9);
                    uint32_t ea = (uint32_t)__shfl((int)ex, sl1, 64);
                    uint32_t eb = (uint32_t)__shfl((int)ex, sl2, 64);
                    uint32_t fa = ea & 0x1FFu, ga = ea >> 9;
                    uint32_t fb = eb & 0x1FFu, gb = eb >> 9;
                    // columns with >=2 exact-pair cells across the full column
                    uint32_t dup = g0 | ga | gb | (f0 & fa) | (f0 & fb) | (fa & fb);
                    uint32_t sK = P & (dup * 0x40201u);
                    K[d1] |= sK; K[d2] |= sK;
                }
            #pragma unroll
            for (int d = 0; d < 9; ++d) {
                uint32_t kc = colfold(K[d]);
                uint32_t cols = kc | (uint32_t)__shfl((int)kc, sl1, 64)
                                   | (uint32_t)__shfl((int)kc, sl2, 64);
                uint32_t em = cols * 0x40201u;
                bd[d] = (bd[d] & ~em) | K[d];
            }
        }

        // ---------- doubles 'box' (band-local) ----------
        {
            uint32_t on = 0, tw = 0, fo = 0;
            #pragma unroll
            for (int d = 0; d < 9; ++d) {
                uint32_t c = on & bd[d];
                on ^= bd[d]; fo |= tw & c; tw ^= c;
            }
            uint32_t ex2 = tw & ~on & ~fo;
            uint32_t Q[9], K[9];
            #pragma unroll
            for (int d = 0; d < 9; ++d) { Q[d] = bd[d] & ex2; K[d] = 0u; }
            #pragma unroll
            for (int d1 = 0; d1 < 9; ++d1)
                #pragma unroll
                for (int d2 = d1 + 1; d2 < 9; ++d2) {
                    uint32_t P = Q[d1] & Q[d2];
                    #pragma unroll
                    for (int k = 0; k < 3; ++k) {
                        uint32_t m = P & (0x1C0E07u << (3 * k));
                        uint32_t s = (m & (m - 1u)) ? m : 0u;
                        K[d1] |= s; K[d2] |= s;
                    }
                }
            #pragma unroll
            for (int d = 0; d < 9; ++d)
                #pragma unroll
                for (int k = 0; k < 3; ++k) {
                    uint32_t bm = 0x1C0E07u << (3 * k);
                    uint32_t t = K[d] & bm;
                    uint32_t mask = t ? (~bm | t) : 0xFFFFFFFFu;
                    bd[d] &= mask;
                }
        }
    } // passes

    // ---------------- solved flag (AND across triple via shuffle) ----------------
    {
        uint32_t on = 0, tw = 0, fo = 0;
        #pragma unroll
        for (int d = 0; d < 9; ++d) {
            uint32_t c = on & bd[d];
            on ^= bd[d]; fo |= tw & c; tw ^= c;
        }
        uint32_t okb = ((on & ~tw & ~fo) == FULL27) ? 1u : 0u;
        uint32_t all = okb & (uint32_t)__shfl((int)okb, sl1, 64)
                           & (uint32_t)__shfl((int)okb, sl2, 64);
        if (valid && band == 0) solved[p] = all ? 1.0f : 0.0f;
    }

    // ---------------- EXPAND (validated r8): block pool -> float4 stores ----------
    // Bit B of bpool == float blockP*729 + B. Zero -> barrier -> atomicOr -> barrier.
    for (int j = threadIdx.x; j < 1914; j += 256) bpool[j] = 0u;
    __syncthreads();
    if (valid) {
        const int pbit = (wv * 21 + trip) * 729;
        #pragma unroll
        for (int d = 0; d < 9; ++d) {
            int bitbase = pbit + d * 81 + band * 27;
            int di = bitbase >> 5;
            int sh = bitbase & 31;
            uint64_t both = (uint64_t)bd[d] << sh;
            atomicOr(&bpool[di], (uint32_t)both);
            atomicOr(&bpool[di + 1], (uint32_t)(both >> 32));
        }
    }
    __syncthreads();
    {
        int nvb = NB - blockP; if (nvb > 84) nvb = 84;       // 84, or 8 in last block
        const int limit4 = nvb * 729 / 4;                    // both cases divisible by 4
        float4* dst4 = (float4*)(out + (size_t)blockP * 729); // 61236 floats/block: 16B-aligned
        #pragma unroll 4
        for (int i = 0; i < 60; ++i) {
            int j = i * 256 + (int)threadIdx.x;
            if (j < limit4) {
                uint32_t nib = (bpool[j >> 3] >> ((j & 7) * 4)) & 0xFu;
                dst4[j] = make_float4((float)(nib & 1u), (float)((nib >> 1) & 1u),
                                      (float)((nib >> 2) & 1u), (float)((nib >> 3) & 1u));
            }
        }
    }
}

extern "C" void kernel_launch(void* const* d_in, const int* in_sizes, int n_in,
                              void* d_out, int out_size, void* d_ws, size_t ws_size,
                              hipStream_t stream) {
    const uint32_t* in = (const uint32_t*)d_in[0];   // float32 bits; nonzero <=> 1.0f
    float* out = (float*)d_out;
    float* solved = out + (size_t)NB * 729;
    // 84 puzzles per 256-thread block (21 per wave) -> ceil(32768/84) = 391 blocks
    sudoku_kernel<<<(NB + 83) / 84, 256, 0, stream>>>(in, out, solved);
}

// Round 12
// 217.693 us; speedup vs baseline: 1.0352x; 1.0352x over previous
//
#include <hip/hip_runtime.h>
#include <stdint.h>

#define NB 32768
#define NPASS 4
#define FULL27 0x07FFFFFFu
#define NBF (NB * 729)     // total floats = 23,887,872

// Per-band bitboard: digit d, band b (rows 3b..3b+2), bit (r*9+c).
// BOX k mask within band: 0x1C0E07 << 3k ; COL c: 0x40201 << c ; ROW r: 0x1FF << 9r
// Flat float layout: puzzle p, digit d, band b, cell j  ==  p*729 + d*81 + b*27 + j.

__device__ __forceinline__ uint32_t colfold(uint32_t w) {
    return (w | (w >> 9) | (w >> 18)) & 0x1FFu;
}
__device__ __forceinline__ uint32_t colmaj2(uint32_t w) {   // columns with >=2 bits in band
    return ((w & (w >> 9)) | ((w | (w >> 9)) & (w >> 18))) & 0x1FFu;
}

// ---------------- FULLY FUSED: pack + solve + expand (r9 structure) ----------------
// Block = 256 threads = 4 waves; 84 puzzles/block (21/wave, 3 lanes per puzzle:
// trip = lane/3, band = lane%3; lane 63 idle).
//   PACK:   r9 ballot pack (best of 3 measured load strategies: 37 vs 44 vs ~69 µs),
//           now SOFTWARE-PIPELINED: chunk c+1's 16 loads issue before chunk c's
//           ballots, keeping ~16 loads in flight across ballot work (r11
//           post-mortem: the phase is chunk-latency-serialized, not
//           width/funnel-bound).
//   SOLVE:  validated r6/r8 logic, cross-band exchange via __shfl, no barriers.
//   EXPAND: validated r8 block-pool float4 writeback.
__global__ __launch_bounds__(256, 1)
void sudoku_kernel(const uint32_t* __restrict__ in, float* __restrict__ out,
                   float* __restrict__ solved) {
    __shared__ uint32_t bpool[1920];        // pack: 4 strips x 480 dw; expand: 1914 dw
    const int lane = threadIdx.x & 63;
    const int wv   = threadIdx.x >> 6;
    const int trip = lane / 3;              // 0..21 (21 = idle lane 63)
    const int band = lane - trip * 3;
    const int bo1 = band == 2 ? 0 : band + 1;
    const int bo2 = band == 0 ? 2 : band - 1;
    int sl1 = trip * 3 + bo1; if (sl1 > 63) sl1 = 63;   // partner lanes
    int sl2 = trip * 3 + bo2; if (sl2 > 63) sl2 = 63;
    const int blockP = blockIdx.x * 84;                 // first puzzle of block
    const int pb = blockP + wv * 21;                    // first puzzle of wave
    const int p = pb + trip;
    const bool valid = (trip < 21) && (p < NB);

    // ---------------- PACK: pipelined coalesced loads -> ballot -> LDS strip ----
    // Wave-local bit j == input float pb*729 + j (j in [0, 15309)).
    {
        const int base = pb * 729;                      // < 24M, fits int
        uint32_t* mypool = &bpool[wv * 480];
        uint32_t v[16], w[16];
        #pragma unroll
        for (int j = 0; j < 16; ++j) {                  // prologue: chunk 0 loads
            int gi = base + j * 64 + lane;
            if (gi >= NBF) gi = NBF - 1;                // tail-block clamp (bits unused)
            v[j] = in[gi];
        }
        #pragma unroll 1
        for (int c = 0; c < 14; ++c) {
            #pragma unroll
            for (int j = 0; j < 16; ++j) {              // prefetch chunk c+1
                int gi = base + ((c + 1) * 16 + j) * 64 + lane;
                if (gi >= NBF) gi = NBF - 1;
                w[j] = in[gi];
            }
            #pragma unroll
            for (int j = 0; j < 16; ++j) {              // ballot chunk c
                unsigned long long m = __ballot(v[j] != 0u);
                if (lane == 0) {
                    int r = c * 16 + j;
                    mypool[2 * r]     = (uint32_t)m;
                    mypool[2 * r + 1] = (uint32_t)(m >> 32);
                }
            }
            #pragma unroll
            for (int j = 0; j < 16; ++j) v[j] = w[j];
        }
        #pragma unroll
        for (int j = 0; j < 16; ++j) {                  // epilogue: chunk 14 ballots
            unsigned long long m = __ballot(v[j] != 0u);
            if (lane == 0) {
                int r = 14 * 16 + j;
                mypool[2 * r]     = (uint32_t)m;
                mypool[2 * r + 1] = (uint32_t)(m >> 32);
            }
        }
    }
    __syncthreads();

    // ---------------- EXTRACT: 9 band-words for this lane's puzzle ----------------
    uint32_t bd[9];
    {
        const uint32_t* mypool = &bpool[wv * 480];
        const int tx = trip > 20 ? 20 : trip;           // keep idle lane 63 in-bounds
        const int bb0 = tx * 729 + band * 27;
        #pragma unroll
        for (int d = 0; d < 9; ++d) {
            int bb = bb0 + d * 81;
            int di = bb >> 5, sh = bb & 31;
            uint64_t both = (uint64_t)mypool[di] | ((uint64_t)mypool[di + 1] << 32);
            bd[d] = (uint32_t)(both >> sh) & FULL27;
        }
    }
    __syncthreads();    // all extraction done before anyone zeroes the pool later

    // ---------------- SOLVE (validated r6/r8 logic, unchanged) ----------------
    #pragma unroll 1
    for (int pass = 0; pass < NPASS; ++pass) {
        // ---------- filter 'box' (band-local) ----------
        {
            uint32_t on = 0, tw = 0, fo = 0;
            #pragma unroll
            for (int d = 0; d < 9; ++d) {
                uint32_t c = on & bd[d];
                on ^= bd[d]; fo |= tw & c; tw ^= c;
            }
            uint32_t ex1 = on & ~tw & ~fo;
            #pragma unroll
            for (int d = 0; d < 9; ++d) {
                uint32_t s = bd[d] & ex1;
                #pragma unroll
                for (int k = 0; k < 3; ++k) {
                    uint32_t bm = 0x1C0E07u << (3 * k);
                    uint32_t sm = s & bm;
                    uint32_t multi = sm & (sm - 1u);
                    uint32_t keep = (sm == 0u) ? 0xFFFFFFFFu : (~bm | (multi ? 0u : sm));
                    bd[d] &= keep;
                }
            }
        }

        // ---------- pointing 'h' (band-local) ----------
        #pragma unroll
        for (int d = 0; d < 9; ++d) {
            uint32_t w = bd[d];
            uint32_t t = (w | (w >> 1) | (w >> 2)) & 0x01249249u;
            uint32_t sum = (t & 0x1FFu) + ((t >> 9) & 0x1FFu) + ((t >> 18) & 0x1FFu);
            uint32_t single = sum & ~(sum >> 1) & 0x49u;
            uint32_t point = t & (single * 0x40201u);
            uint32_t clearm = 0;
            #pragma unroll
            for (int r = 0; r < 3; ++r) {
                uint32_t pr = (point >> (9 * r)) & 0x1FFu;
                uint32_t multi = pr & (pr - 1u);
                uint32_t segkeep = multi ? 0u : pr * 7u;
                uint32_t rc = pr ? ((0x1FFu & ~segkeep) << (9 * r)) : 0u;
                clearm |= rc;
            }
            bd[d] = w & ~clearm;
        }

        // ---------- pointing 'v' (cross-band via shuffle) ----------
        {
            uint32_t pnt[9];
            #pragma unroll
            for (int d = 0; d < 9; ++d) {
                uint32_t w = bd[d];
                uint32_t q = colfold(w);
                uint32_t u = (q & 0x49u) + ((q >> 1) & 0x49u) + ((q >> 2) & 0x49u);
                uint32_t single = u & ~(u >> 1) & 0x49u;
                pnt[d] = q & (single * 7u);
            }
            #pragma unroll
            for (int d = 0; d < 9; ++d) {
                uint32_t o = (uint32_t)__shfl((int)pnt[d], sl1, 64) |
                             (uint32_t)__shfl((int)pnt[d], sl2, 64);
                bd[d] &= ~(o * 0x40201u);
            }
        }

        // ---------- unique 'h' (band-local) ----------
        {
            uint32_t hid[9], has = 0;
            #pragma unroll
            for (int d = 0; d < 9; ++d) {
                uint32_t w = bd[d], h = 0;
                #pragma unroll
                for (int r = 0; r < 3; ++r) {
                    uint32_t x = w & (0x1FFu << (9 * r));
                    h |= (x & (x - 1u)) ? 0u : x;
                }
                hid[d] = h; has |= h;
            }
            #pragma unroll
            for (int d = 0; d < 9; ++d) bd[d] = (bd[d] & ~has) | hid[d];
        }

        // ---------- unique 'v' (cross-band via shuffle) ----------
        {
            uint32_t hid[9], has = 0;
            #pragma unroll
            for (int d = 0; d < 9; ++d) {
                uint32_t w = bd[d];
                uint32_t q0 = colfold(w), m0 = colmaj2(w);
                uint32_t ex = q0 | (m0 << 9);
                uint32_t ea = (uint32_t)__shfl((int)ex, sl1, 64);
                uint32_t eb = (uint32_t)__shfl((int)ex, sl2, 64);
                uint32_t qa = ea & 0x1FFu, ma = ea >> 9;
                uint32_t qb = eb & 0x1FFu, mb = eb >> 9;
                uint32_t ge2 = m0 | ma | mb | (q0 & qa) | (q0 & qb) | (qa & qb);
                uint32_t ex1c = (q0 | qa | qb) & ~ge2;   // column total count == 1
                hid[d] = w & ((ex1c & q0) * 0x40201u);
                has |= hid[d];
            }
            #pragma unroll
            for (int d = 0; d < 9; ++d) bd[d] = (bd[d] & ~has) | hid[d];
        }

        // ---------- unique 'box' (band-local) ----------
        {
            uint32_t hid[9], has = 0;
            #pragma unroll
            for (int d = 0; d < 9; ++d) {
                uint32_t w = bd[d], h = 0;
                #pragma unroll
                for (int k = 0; k < 3; ++k) {
                    uint32_t x = w & (0x1C0E07u << (3 * k));
                    h |= (x & (x - 1u)) ? 0u : x;
                }
                hid[d] = h; has |= h;
            }
            #pragma unroll
            for (int d = 0; d < 9; ++d) bd[d] = (bd[d] & ~has) | hid[d];
        }

        // ---------- doubles 'v' twice (cross-band via shuffle) ----------
        #pragma unroll 1
        for (int rep = 0; rep < 2; ++rep) {
            uint32_t on = 0, tw = 0, fo = 0;
            #pragma unroll
            for (int d = 0; d < 9; ++d) {
                uint32_t c = on & bd[d];
                on ^= bd[d]; fo |= tw & c; tw ^= c;
            }
            uint32_t ex2 = tw & ~on & ~fo;
            uint32_t Q[9], K[9];
            #pragma unroll
            for (int d = 0; d < 9; ++d) { Q[d] = bd[d] & ex2; K[d] = 0u; }
            #pragma unroll
            for (int d1 = 0; d1 < 9; ++d1)
                #pragma unroll
                for (int d2 = d1 + 1; d2 < 9; ++d2) {
                    uint32_t P = Q[d1] & Q[d2];
                    uint32_t f0 = colfold(P), g0 = colmaj2(P);
                    uint32_t ex = f0 | (g0 << 9);
                    uint32_t ea = (uint32_t)__shfl((int)ex, sl1, 64);
                    uint32_t eb = (uint32_t)__shfl((int)ex, sl2, 64);
                    uint32_t fa = ea & 0x1FFu, ga = ea >> 9;
                    uint32_t fb = eb & 0x1FFu, gb = eb >> 9;
                    // columns with >=2 exact-pair cells across the full column
                    uint32_t dup = g0 | ga | gb | (f0 & fa) | (f0 & fb) | (fa & fb);
                    uint32_t sK = P & (dup * 0x40201u);
                    K[d1] |= sK; K[d2] |= sK;
                }
            #pragma unroll
            for (int d = 0; d < 9; ++d) {
                uint32_t kc = colfold(K[d]);
                uint32_t cols = kc | (uint32_t)__shfl((int)kc, sl1, 64)
                                   | (uint32_t)__shfl((int)kc, sl2, 64);
                uint32_t em = cols * 0x40201u;
                bd[d] = (bd[d] & ~em) | K[d];
            }
        }

        // ---------- doubles 'box' (band-local) ----------
        {
            uint32_t on = 0, tw = 0, fo = 0;
            #pragma unroll
            for (int d = 0; d < 9; ++d) {
                uint32_t c = on & bd[d];
                on ^= bd[d]; fo |= tw & c; tw ^= c;
            }
            uint32_t ex2 = tw & ~on & ~fo;
            uint32_t Q[9], K[9];
            #pragma unroll
            for (int d = 0; d < 9; ++d) { Q[d] = bd[d] & ex2; K[d] = 0u; }
            #pragma unroll
            for (int d1 = 0; d1 < 9; ++d1)
                #pragma unroll
                for (int d2 = d1 + 1; d2 < 9; ++d2) {
                    uint32_t P = Q[d1] & Q[d2];
                    #pragma unroll
                    for (int k = 0; k < 3; ++k) {
                        uint32_t m = P & (0x1C0E07u << (3 * k));
                        uint32_t s = (m & (m - 1u)) ? m : 0u;
                        K[d1] |= s; K[d2] |= s;
                    }
                }
            #pragma unroll
            for (int d = 0; d < 9; ++d)
                #pragma unroll
                for (int k = 0; k < 3; ++k) {
                    uint32_t bm = 0x1C0E07u << (3 * k);
                    uint32_t t = K[d] & bm;
                    uint32_t mask = t ? (~bm | t) : 0xFFFFFFFFu;
                    bd[d] &= mask;
                }
        }
    } // passes

    // ---------------- solved flag (AND across triple via shuffle) ----------------
    {
        uint32_t on = 0, tw = 0, fo = 0;
        #pragma unroll
        for (int d = 0; d < 9; ++d) {
            uint32_t c = on & bd[d];
            on ^= bd[d]; fo |= tw & c; tw ^= c;
        }
        uint32_t okb = ((on & ~tw & ~fo) == FULL27) ? 1u : 0u;
        uint32_t all = okb & (uint32_t)__shfl((int)okb, sl1, 64)
                           & (uint32_t)__shfl((int)okb, sl2, 64);
        if (valid && band == 0) solved[p] = all ? 1.0f : 0.0f;
    }

    // ---------------- EXPAND (validated r8): block pool -> float4 stores ----------
    // Bit B of bpool == float blockP*729 + B. Zero -> barrier -> atomicOr -> barrier.
    for (int j = threadIdx.x; j < 1914; j += 256) bpool[j] = 0u;
    __syncthreads();
    if (valid) {
        const int pbit = (wv * 21 + trip) * 729;
        #pragma unroll
        for (int d = 0; d < 9; ++d) {
            int bitbase = pbit + d * 81 + band * 27;
            int di = bitbase >> 5;
            int sh = bitbase & 31;
            uint64_t both = (uint64_t)bd[d] << sh;
            atomicOr(&bpool[di], (uint32_t)both);
            atomicOr(&bpool[di + 1], (uint32_t)(both >> 32));
        }
    }
    __syncthreads();
    {
        int nvb = NB - blockP; if (nvb > 84) nvb = 84;       // 84, or 8 in last block
        const int limit4 = nvb * 729 / 4;                    // both cases divisible by 4
        float4* dst4 = (float4*)(out + (size_t)blockP * 729); // 61236 floats/block: 16B-aligned
        #pragma unroll 4
        for (int i = 0; i < 60; ++i) {
            int j = i * 256 + (int)threadIdx.x;
            if (j < limit4) {
                uint32_t nib = (bpool[j >> 3] >> ((j & 7) * 4)) & 0xFu;
                dst4[j] = make_float4((float)(nib & 1u), (float)((nib >> 1) & 1u),
                                      (float)((nib >> 2) & 1u), (float)((nib >> 3) & 1u));
            }
        }
    }
}

extern "C" void kernel_launch(void* const* d_in, const int* in_sizes, int n_in,
                              void* d_out, int out_size, void* d_ws, size_t ws_size,
                              hipStream_t stream) {
    const uint32_t* in = (const uint32_t*)d_in[0];   // float32 bits; nonzero <=> 1.0f
    float* out = (float*)d_out;
    float* solved = out + (size_t)NB * 729;
    // 84 puzzles per 256-thread block (21 per wave) -> ceil(32768/84) = 391 blocks
    sudoku_kernel<<<(NB + 83) / 84, 256, 0, stream>>>(in, out, solved);
}

// Round 13
// 216.616 us; speedup vs baseline: 1.0404x; 1.0050x over previous
//
#include <hip/hip_runtime.h>
#include <stdint.h>

#define NB 32768
#define NPASS 4
#define FULL27 0x07FFFFFFu
#define NBF (NB * 729)     // total floats = 23,887,872
#define PPW 20             // puzzles per wave-block (20*729 = 14580 ≡ 0 mod 4 -> aligned float4)
#define NBLK ((NB + PPW - 1) / PPW)   // 1639 blocks

// Per-band bitboard: digit d, band b (rows 3b..3b+2), bit (r*9+c).
// BOX k mask within band: 0x1C0E07 << 3k ; COL c: 0x40201 << c ; ROW r: 0x1FF << 9r
// Flat float layout: puzzle p, digit d, band b, cell j  ==  p*729 + d*81 + b*27 + j.

__device__ __forceinline__ uint32_t colfold(uint32_t w) {
    return (w | (w >> 9) | (w >> 18)) & 0x1FFu;
}
__device__ __forceinline__ uint32_t colmaj2(uint32_t w) {   // columns with >=2 bits in band
    return ((w & (w >> 9)) | ((w | (w >> 9)) & (w >> 18))) & 0x1FFu;
}

// ---------------- FULLY FUSED, 1-WAVE BLOCKS: pack + solve + expand ----------------
// r12 post-mortem: the limiter is BLOCK-GRANULARITY LOAD IMBALANCE (391 4-wave
// blocks on 256 CUs -> 2-round makespan, 76% ceiling), not any single phase.
// Fix: 64-thread blocks (1 wave, 20 puzzles) -> 1639 fine-grained blocks the
// dispatcher backfills dynamically. 20 puzzles (not 21) keeps every block's
// 14580-float window 16B-aligned for float4 expand. Phases byte-equivalent to
// r9/r8 validated code, rebased to a wave-private 456-dword pool.
__global__ __launch_bounds__(64)
void sudoku_kernel(const uint32_t* __restrict__ in, float* __restrict__ out,
                   float* __restrict__ solved) {
    __shared__ uint32_t pool[460];          // 14580 bits = 456 dw (+pad)
    const int lane = threadIdx.x;
    const int trip = lane / 3;              // 0..21 (20,21 = idle lanes 60..63)
    const int band = lane - trip * 3;
    const int bo1 = band == 2 ? 0 : band + 1;
    const int bo2 = band == 0 ? 2 : band - 1;
    int sl1 = trip * 3 + bo1; if (sl1 > 63) sl1 = 63;   // partner lanes
    int sl2 = trip * 3 + bo2; if (sl2 > 63) sl2 = 63;
    const int p0 = blockIdx.x * PPW;        // first puzzle of block
    const int p = p0 + trip;
    const bool valid = (trip < PPW) && (p < NB);

    // ---------------- PACK: coalesced loads -> ballot -> wave-private pool ----------
    // Pool bit j == input float p0*729 + j (j in [0, 14580)). 228 rounds of 64.
    {
        const int base = p0 * 729;                      // < 24M, fits int
        #pragma unroll 1
        for (int c = 0; c < 14; ++c) {                  // 14 chunks x 16 rounds
            uint32_t v[16];
            #pragma unroll
            for (int j = 0; j < 16; ++j) {
                int gi = base + (c * 16 + j) * 64 + lane;
                if (gi >= NBF) gi = NBF - 1;            // tail clamp (bits unused)
                v[j] = in[gi];
            }
            #pragma unroll
            for (int j = 0; j < 16; ++j) {
                unsigned long long m = __ballot(v[j] != 0u);
                if (lane == 0) {
                    int r = c * 16 + j;
                    pool[2 * r]     = (uint32_t)m;
                    pool[2 * r + 1] = (uint32_t)(m >> 32);
                }
            }
        }
        {   // rounds 224..227
            uint32_t v[4];
            #pragma unroll
            for (int j = 0; j < 4; ++j) {
                int gi = base + (224 + j) * 64 + lane;
                if (gi >= NBF) gi = NBF - 1;
                v[j] = in[gi];
            }
            #pragma unroll
            for (int j = 0; j < 4; ++j) {
                unsigned long long m = __ballot(v[j] != 0u);
                if (lane == 0) {
                    int r = 224 + j;
                    pool[2 * r]     = (uint32_t)m;
                    pool[2 * r + 1] = (uint32_t)(m >> 32);
                }
            }
        }
    }
    __syncthreads();

    // ---------------- EXTRACT: 9 band-words for this lane's puzzle ----------------
    uint32_t bd[9];
    {
        const int tx = trip >= PPW ? PPW - 1 : trip;    // keep idle lanes in-bounds
        const int bb0 = tx * 729 + band * 27;
        #pragma unroll
        for (int d = 0; d < 9; ++d) {
            int bb = bb0 + d * 81;
            int di = bb >> 5, sh = bb & 31;
            uint64_t both = (uint64_t)pool[di] | ((uint64_t)pool[di + 1] << 32);
            bd[d] = (uint32_t)(both >> sh) & FULL27;
        }
    }
    __syncthreads();    // extraction done before the pool is zeroed for expand

    // ---------------- SOLVE (validated r6/r8 logic, unchanged) ----------------
    #pragma unroll 1
    for (int pass = 0; pass < NPASS; ++pass) {
        // ---------- filter 'box' (band-local) ----------
        {
            uint32_t on = 0, tw = 0, fo = 0;
            #pragma unroll
            for (int d = 0; d < 9; ++d) {
                uint32_t c = on & bd[d];
                on ^= bd[d]; fo |= tw & c; tw ^= c;
            }
            uint32_t ex1 = on & ~tw & ~fo;
            #pragma unroll
            for (int d = 0; d < 9; ++d) {
                uint32_t s = bd[d] & ex1;
                #pragma unroll
                for (int k = 0; k < 3; ++k) {
                    uint32_t bm = 0x1C0E07u << (3 * k);
                    uint32_t sm = s & bm;
                    uint32_t multi = sm & (sm - 1u);
                    uint32_t keep = (sm == 0u) ? 0xFFFFFFFFu : (~bm | (multi ? 0u : sm));
                    bd[d] &= keep;
                }
            }
        }

        // ---------- pointing 'h' (band-local) ----------
        #pragma unroll
        for (int d = 0; d < 9; ++d) {
            uint32_t w = bd[d];
            uint32_t t = (w | (w >> 1) | (w >> 2)) & 0x01249249u;
            uint32_t sum = (t & 0x1FFu) + ((t >> 9) & 0x1FFu) + ((t >> 18) & 0x1FFu);
            uint32_t single = sum & ~(sum >> 1) & 0x49u;
            uint32_t point = t & (single * 0x40201u);
            uint32_t clearm = 0;
            #pragma unroll
            for (int r = 0; r < 3; ++r) {
                uint32_t pr = (point >> (9 * r)) & 0x1FFu;
                uint32_t multi = pr & (pr - 1u);
                uint32_t segkeep = multi ? 0u : pr * 7u;
                uint32_t rc = pr ? ((0x1FFu & ~segkeep) << (9 * r)) : 0u;
                clearm |= rc;
            }
            bd[d] = w & ~clearm;
        }

        // ---------- pointing 'v' (cross-band via shuffle) ----------
        {
            uint32_t pnt[9];
            #pragma unroll
            for (int d = 0; d < 9; ++d) {
                uint32_t w = bd[d];
                uint32_t q = colfold(w);
                uint32_t u = (q & 0x49u) + ((q >> 1) & 0x49u) + ((q >> 2) & 0x49u);
                uint32_t single = u & ~(u >> 1) & 0x49u;
                pnt[d] = q & (single * 7u);
            }
            #pragma unroll
            for (int d = 0; d < 9; ++d) {
                uint32_t o = (uint32_t)__shfl((int)pnt[d], sl1, 64) |
                             (uint32_t)__shfl((int)pnt[d], sl2, 64);
                bd[d] &= ~(o * 0x40201u);
            }
        }

        // ---------- unique 'h' (band-local) ----------
        {
            uint32_t hid[9], has = 0;
            #pragma unroll
            for (int d = 0; d < 9; ++d) {
                uint32_t w = bd[d], h = 0;
                #pragma unroll
                for (int r = 0; r < 3; ++r) {
                    uint32_t x = w & (0x1FFu << (9 * r));
                    h |= (x & (x - 1u)) ? 0u : x;
                }
                hid[d] = h; has |= h;
            }
            #pragma unroll
            for (int d = 0; d < 9; ++d) bd[d] = (bd[d] & ~has) | hid[d];
        }

        // ---------- unique 'v' (cross-band via shuffle) ----------
        {
            uint32_t hid[9], has = 0;
            #pragma unroll
            for (int d = 0; d < 9; ++d) {
                uint32_t w = bd[d];
                uint32_t q0 = colfold(w), m0 = colmaj2(w);
                uint32_t ex = q0 | (m0 << 9);
                uint32_t ea = (uint32_t)__shfl((int)ex, sl1, 64);
                uint32_t eb = (uint32_t)__shfl((int)ex, sl2, 64);
                uint32_t qa = ea & 0x1FFu, ma = ea >> 9;
                uint32_t qb = eb & 0x1FFu, mb = eb >> 9;
                uint32_t ge2 = m0 | ma | mb | (q0 & qa) | (q0 & qb) | (qa & qb);
                uint32_t ex1c = (q0 | qa | qb) & ~ge2;   // column total count == 1
                hid[d] = w & ((ex1c & q0) * 0x40201u);
                has |= hid[d];
            }
            #pragma unroll
            for (int d = 0; d < 9; ++d) bd[d] = (bd[d] & ~has) | hid[d];
        }

        // ---------- unique 'box' (band-local) ----------
        {
            uint32_t hid[9], has = 0;
            #pragma unroll
            for (int d = 0; d < 9; ++d) {
                uint32_t w = bd[d], h = 0;
                #pragma unroll
                for (int k = 0; k < 3; ++k) {
                    uint32_t x = w & (0x1C0E07u << (3 * k));
                    h |= (x & (x - 1u)) ? 0u : x;
                }
                hid[d] = h; has |= h;
            }
            #pragma unroll
            for (int d = 0; d < 9; ++d) bd[d] = (bd[d] & ~has) | hid[d];
        }

        // ---------- doubles 'v' twice (cross-band via shuffle) ----------
        #pragma unroll 1
        for (int rep = 0; rep < 2; ++rep) {
            uint32_t on = 0, tw = 0, fo = 0;
            #pragma unroll
            for (int d = 0; d < 9; ++d) {
                uint32_t c = on & bd[d];
                on ^= bd[d]; fo |= tw & c; tw ^= c;
            }
            uint32_t ex2 = tw & ~on & ~fo;
            uint32_t Q[9], K[9];
            #pragma unroll
            for (int d = 0; d < 9; ++d) { Q[d] = bd[d] & ex2; K[d] = 0u; }
            #pragma unroll
            for (int d1 = 0; d1 < 9; ++d1)
                #pragma unroll
                for (int d2 = d1 + 1; d2 < 9; ++d2) {
                    uint32_t P = Q[d1] & Q[d2];
                    uint32_t f0 = colfold(P), g0 = colmaj2(P);
                    uint32_t ex = f0 | (g0 << 9);
                    uint32_t ea = (uint32_t)__shfl((int)ex, sl1, 64);
                    uint32_t eb = (uint32_t)__shfl((int)ex, sl2, 64);
                    uint32_t fa = ea & 0x1FFu, ga = ea >> 9;
                    uint32_t fb = eb & 0x1FFu, gb = eb >> 9;
                    // columns with >=2 exact-pair cells across the full column
                    uint32_t dup = g0 | ga | gb | (f0 & fa) | (f0 & fb) | (fa & fb);
                    uint32_t sK = P & (dup * 0x40201u);
                    K[d1] |= sK; K[d2] |= sK;
                }
            #pragma unroll
            for (int d = 0; d < 9; ++d) {
                uint32_t kc = colfold(K[d]);
                uint32_t cols = kc | (uint32_t)__shfl((int)kc, sl1, 64)
                                   | (uint32_t)__shfl((int)kc, sl2, 64);
                uint32_t em = cols * 0x40201u;
                bd[d] = (bd[d] & ~em) | K[d];
            }
        }

        // ---------- doubles 'box' (band-local) ----------
        {
            uint32_t on = 0, tw = 0, fo = 0;
            #pragma unroll
            for (int d = 0; d < 9; ++d) {
                uint32_t c = on & bd[d];
                on ^= bd[d]; fo |= tw & c; tw ^= c;
            }
            uint32_t ex2 = tw & ~on & ~fo;
            uint32_t Q[9], K[9];
            #pragma unroll
            for (int d = 0; d < 9; ++d) { Q[d] = bd[d] & ex2; K[d] = 0u; }
            #pragma unroll
            for (int d1 = 0; d1 < 9; ++d1)
                #pragma unroll
                for (int d2 = d1 + 1; d2 < 9; ++d2) {
                    uint32_t P = Q[d1] & Q[d2];
                    #pragma unroll
                    for (int k = 0; k < 3; ++k) {
                        uint32_t m = P & (0x1C0E07u << (3 * k));
                        uint32_t s = (m & (m - 1u)) ? m : 0u;
                        K[d1] |= s; K[d2] |= s;
                    }
                }
            #pragma unroll
            for (int d = 0; d < 9; ++d)
                #pragma unroll
                for (int k = 0; k < 3; ++k) {
                    uint32_t bm = 0x1C0E07u << (3 * k);
                    uint32_t t = K[d] & bm;
                    uint32_t mask = t ? (~bm | t) : 0xFFFFFFFFu;
                    bd[d] &= mask;
                }
        }
    } // passes

    // ---------------- solved flag (AND across triple via shuffle) ----------------
    {
        uint32_t on = 0, tw = 0, fo = 0;
        #pragma unroll
        for (int d = 0; d < 9; ++d) {
            uint32_t c = on & bd[d];
            on ^= bd[d]; fo |= tw & c; tw ^= c;
        }
        uint32_t okb = ((on & ~tw & ~fo) == FULL27) ? 1u : 0u;
        uint32_t all = okb & (uint32_t)__shfl((int)okb, sl1, 64)
                           & (uint32_t)__shfl((int)okb, sl2, 64);
        if (valid && band == 0) solved[p] = all ? 1.0f : 0.0f;
    }

    // ---------------- EXPAND (validated r8, rebased): pool -> float4 stores ----------
    // Bit B of pool == float p0*729 + B. Zero -> barrier -> atomicOr -> barrier.
    for (int j = lane; j < 456; j += 64) pool[j] = 0u;
    __syncthreads();
    if (valid) {
        const int pbit = trip * 729;
        #pragma unroll
        for (int d = 0; d < 9; ++d) {
            int bitbase = pbit + d * 81 + band * 27;
            int di = bitbase >> 5;
            int sh = bitbase & 31;
            uint64_t both = (uint64_t)bd[d] << sh;
            atomicOr(&pool[di], (uint32_t)both);
            atomicOr(&pool[di + 1], (uint32_t)(both >> 32));
        }
    }
    __syncthreads();
    {
        int nv = NB - p0; if (nv > PPW) nv = PPW;            // 20, or 8 in last block
        const int limit4 = nv * 729 / 4;                     // 3645 or 1458 (both exact)
        float4* dst4 = (float4*)(out + (size_t)p0 * 729);    // p0*729 ≡ 0 mod 4: aligned
        #pragma unroll 4
        for (int i = 0; i < 57; ++i) {
            int j = i * 64 + lane;
            if (j < limit4) {
                uint32_t nib = (pool[j >> 3] >> ((j & 7) * 4)) & 0xFu;
                dst4[j] = make_float4((float)(nib & 1u), (float)((nib >> 1) & 1u),
                                      (float)((nib >> 2) & 1u), (float)((nib >> 3) & 1u));
            }
        }
    }
}

extern "C" void kernel_launch(void* const* d_in, const int* in_sizes, int n_in,
                              void* d_out, int out_size, void* d_ws, size_t ws_size,
                              hipStream_t stream) {
    const uint32_t* in = (const uint32_t*)d_in[0];   // float32 bits; nonzero <=> 1.0f
    float* out = (float*)d_out;
    float* solved = out + (size_t)NB * 729;
    // 1639 one-wave blocks (20 puzzles each) -> dynamic CU backfill
    sudoku_kernel<<<NBLK, 64, 0, stream>>>(in, out, solved);
}